// Round 14
// baseline (51.511 us; speedup 1.0000x reference)
//
#include <hip/hip_runtime.h>
#include <hip/hip_bf16.h>

#define NJ 24
#define TLEN 25000
#define NB 4
#define CHUNKS 20
#define NWPB (CHUNKS*4)           // waves per (b,j) = 80
#define NITERS ((TLEN+63)/64)     // 391

typedef short short8 __attribute__((ext_vector_type(8)));
typedef short s16x2 __attribute__((ext_vector_type(2)));
typedef float f32x16 __attribute__((ext_vector_type(16)));

union FragU { unsigned u[4]; short8 s; };

// Fast f32x2 -> packed bf16x2, round-half-up. 3 VALU ops. (Do NOT use
// inline-asm v_cvt_pk_bf16_f32 — NaN'd on this toolchain, R5: same
// missing-hazard class as R13.)
__device__ __forceinline__ unsigned pack2(float a, float b){
    unsigned ua = __float_as_uint(a) + 0x8000u;
    unsigned ub = __float_as_uint(b) + 0x8000u;
    return __builtin_amdgcn_perm(ub, ua, 0x07060302u);
}
__device__ __forceinline__ float bflo(unsigned u){
    union { unsigned v; float f; } t; t.v = u << 16; return t.f;
}

// packed bf16 relu via i16 max (bf16 bit patterns order as i16; negatives -> +0.0)
__device__ __forceinline__ unsigned pkrelu(unsigned x){
    union { unsigned u; s16x2 v; } a, r;
    a.u = x;
    s16x2 z; z[0] = 0; z[1] = 0;
    r.v = __builtin_elementwise_max(a.v, z);
    return r.u;
}

// R14: VGPR-form MFMA via inline asm WITH EXPLICIT HAZARD WAITS.
// R13 (same asm, no waits) produced garbage: inline asm is opaque to the
// compiler's MFMA hazard recognizer, so it cannot insert the required
// wait states between v_mfma's D write and subsequent VALU reads (CDNA
// MFMA writes are NOT hardware-interlocked). Fix: s_nop 1 before (covers
// VALU-write -> MFMA SrcA/B read, 2cyc) and 3x s_nop 7 after (24cyc >=
// worst-case 32x32 MFMA -> VALU read hazard ~18cyc) INSIDE the block.
// s_nop is wave-local (other waves fill it); the v_accvgpr_read traffic
// it replaces occupied the shared VALU pipe (~350 unfillable cyc/trip,
// the R9-R12 invariant stall). "v" constraints = arch VGPRs (legal for
// C/D on gfx950 unified file, ISA §10); "=&v" earlyclobber keeps D
// disjoint from A/B/C.
__device__ __forceinline__ f32x16 mfma_v(const FragU &a, const FragU &b, const f32x16 &c){
    f32x16 d;
    asm("s_nop 1\n\t"
        "v_mfma_f32_32x32x16_bf16 %0, %1, %2, %3\n\t"
        "s_nop 7\n\t"
        "s_nop 7\n\t"
        "s_nop 7"
        : "=&v"(d)
        : "v"(a.s), "v"(b.s), "v"(c));
    return d;
}

// round-to-bf16 then packed relu; zero-shuffle layer chaining (pi-permuted
// channel labels compensated in the weight gather).
__device__ __forceinline__ void relu_pack(const f32x16 &acc, FragU &k0, FragU &k1){
    unsigned w[8];
    #pragma unroll
    for (int i = 0; i < 8; ++i) w[i] = pkrelu(pack2(acc[2*i], acc[2*i+1]));
    k0.u[0]=w[0]; k0.u[1]=w[1]; k0.u[2]=w[2]; k0.u[3]=w[3];
    k1.u[0]=w[4]; k1.u[1]=w[5]; k1.u[2]=w[6]; k1.u[3]=w[7];
}

// launch_bounds(256,1): full register budget for the all-VGPR plan.
// (256,4) spilled catastrophically in R2 — never tighten.
__global__ __launch_bounds__(256, 1) void ptf_decoder_kernel(
    const float* __restrict__ p,    const float* __restrict__ c,
    const float* __restrict__ Wproj,const float* __restrict__ bproj,
    const float* __restrict__ Wp,   const float* __restrict__ bp,
    const float* __restrict__ W0,   const float* __restrict__ b0,
    const float* __restrict__ W1,   const float* __restrict__ b1,
    const float* __restrict__ W2,   const float* __restrict__ b2,
    const float* __restrict__ Wout, const float* __restrict__ bout,
    float* __restrict__ out)
{
    __shared__ __align__(16) float ldsW[3][32][36];
    __shared__ __align__(16) float ldsWp[32][8];
    __shared__ __align__(16) float ldsB[3][32];
    __shared__ __align__(16) float ldsWo[32];

    const int tid = threadIdx.x;
    const int bj  = blockIdx.x % (NB*NJ);
    const int sub = blockIdx.x / (NB*NJ);
    const int b   = bj / NJ;
    const int j   = bj % NJ;

    // ---- stage this joint's weights into LDS (coalesced) ----
    {
        const float* Wl[3] = {W0, W1, W2};
        #pragma unroll
        for (int L = 0; L < 3; ++L) {
            int row = tid >> 3, c4 = tid & 7;
            float4 v = *reinterpret_cast<const float4*>(Wl[L] + ((size_t)(j*32 + row))*32 + c4*4);
            *reinterpret_cast<float4*>(&ldsW[L][row][c4*4]) = v;
        }
        {
            int row = tid >> 3, i8 = tid & 7;
            // col 7 carries b_p (first-layer bias rides k=7 with input 1.0)
            ldsWp[row][i8] = (i8 < 7) ? Wp[((size_t)(j*32 + row))*7 + i8]
                                      : bp[j*32 + row];
        }
        if      (tid < 32)  ldsB[0][tid]      = b0[j*32 + tid];
        else if (tid < 64)  ldsB[1][tid-32]   = b1[j*32 + tid-32];
        else if (tid < 96)  ldsB[2][tid-64]   = b2[j*32 + tid-64];
        else if (tid < 128) ldsWo[tid-96]     = Wout[j*32 + tid-96];
    }
    __syncthreads();

    const int lane = tid & 63;
    const int row  = lane & 31;
    const int h    = lane >> 5;

    // ---- per-lane weight fragments (bf16 hi only), pi-permuted k labels ----
    FragU whi[3][2];
    #pragma unroll
    for (int L = 0; L < 3; ++L) {
        #pragma unroll
        for (int kh = 0; kh < 2; ++kh) {
            const int g  = kh*2 + h;
            const int cA = (g >> 1)*4 + (g & 1);
            const float* base = &ldsW[L][row][0];
            float4 x = *reinterpret_cast<const float4*>(base + cA*4);
            float4 y = *reinterpret_cast<const float4*>(base + (cA+2)*4);
            whi[L][kh].u[0] = pack2(x.x, x.y);
            whi[L][kh].u[1] = pack2(x.z, x.w);
            whi[L][kh].u[2] = pack2(y.x, y.y);
            whi[L][kh].u[3] = pack2(y.z, y.w);
        }
    }
    // output layer: wo broadcast to all 32 rows, same pi-compensated gather
    FragU woF[2];
    #pragma unroll
    for (int kh = 0; kh < 2; ++kh) {
        const int g  = kh*2 + h;
        const int cA = (g >> 1)*4 + (g & 1);
        float4 x = *reinterpret_cast<const float4*>(&ldsWo[cA*4]);
        float4 y = *reinterpret_cast<const float4*>(&ldsWo[(cA+2)*4]);
        woF[kh].u[0] = pack2(x.x, x.y);
        woF[kh].u[1] = pack2(x.z, x.w);
        woF[kh].u[2] = pack2(y.x, y.y);
        woF[kh].u[3] = pack2(y.z, y.w);
    }
    // first layer: bf16 hi only (verified absmax 0.0156, 2.2x margin)
    FragU wphi;
    {
        float4 x = make_float4(0,0,0,0), y = make_float4(0,0,0,0);
        if (lane < 32) {
            x = *reinterpret_cast<const float4*>(&ldsWp[row][0]);
            y = *reinterpret_cast<const float4*>(&ldsWp[row][4]);
        }
        wphi.u[0] = pack2(x.x, x.y);
        wphi.u[1] = pack2(x.z, x.w);
        wphi.u[2] = pack2(y.x, y.y);
        wphi.u[3] = pack2(y.z, y.w);
    }

    // shared zero C (persistent VGPRs)
    f32x16 kZero;
    #pragma unroll
    for (int r = 0; r < 16; ++r) kZero[r] = 0.f;

    // ---- hidden-layer bias SURFACES precomputed once (prologue MFMA),
    //      persistent f32x16 in VGPRs: removes 3 MFMAs/trip from the loop ----
    f32x16 biasS[3];
    #pragma unroll
    for (int L = 0; L < 3; ++L) {
        float bl = (h == 0) ? ldsB[L][row] : 0.f;
        unsigned t = pack2(bl, 0.f);
        float res = bl - bflo(t);
        unsigned biasw = (h == 0) ? pack2(bl, res) : 0u;
        FragU ba; ba.u[0] = biasw; ba.u[1] = 0; ba.u[2] = 0; ba.u[3] = 0;
        FragU on; on.u[0] = (h == 0) ? 0x3f803f80u : 0u; on.u[1] = 0; on.u[2] = 0; on.u[3] = 0;
        biasS[L] = mfma_v(ba, on, kZero);
    }

    // ---- c projection: c_proj[o] = dot(c[b], Wproj[j][o]) + bproj ----
    float cacc0, cacc1, cacc2, cacc3;
    {
        const float* cb  = c + (size_t)b*128;
        const float* wpj = Wproj + (size_t)j*4*128;
        float cl = cb[lane], chv = cb[lane + 64];
        cacc0 = cl*wpj[0*128+lane] + chv*wpj[0*128+lane+64];
        cacc1 = cl*wpj[1*128+lane] + chv*wpj[1*128+lane+64];
        cacc2 = cl*wpj[2*128+lane] + chv*wpj[2*128+lane+64];
        cacc3 = cl*wpj[3*128+lane] + chv*wpj[3*128+lane+64];
        #pragma unroll
        for (int off = 32; off >= 1; off >>= 1) {
            cacc0 += __shfl_xor(cacc0, off, 64);
            cacc1 += __shfl_xor(cacc1, off, 64);
            cacc2 += __shfl_xor(cacc2, off, 64);
            cacc3 += __shfl_xor(cacc3, off, 64);
        }
        cacc0 += bproj[j*4+0]; cacc1 += bproj[j*4+1];
        cacc2 += bproj[j*4+2]; cacc3 += bproj[j*4+3];
    }
    const float c0v = (lane < 32) ? cacc0 : 0.f;
    unsigned wc2h = pack2(cacc1, cacc2);
    unsigned wc3h = pack2(cacc3, 1.0f);   // k6=c3, k7=1.0 (bias slot)
    if (lane >= 32) { wc2h = 0; wc3h = 0; }
    const float bo = bout[j];

    // ---- main loop over 64-column tiles ----
    const float* pb0 = p + ((size_t)(b*(NJ*3) + j*3 + 0))*TLEN;
    const float* pb1 = pb0 + TLEN;
    const float* pb2 = pb1 + TLEN;
    float* ob = out + ((size_t)(b*NJ + j))*TLEN;

    const int w0idx = sub*4 + (tid >> 6);

    auto loadP = [&](int itx, float&x0,float&x1,float&x2,float&x3,float&x4,float&x5){
        x0=0.f;x1=0.f;x2=0.f;x3=0.f;x4=0.f;x5=0.f;
        if (itx < NITERS && lane < 32) {
            int tA = itx*64 + lane;
            int tB = tA + 32;
            tA = tA < TLEN ? tA : TLEN-1;
            tB = tB < TLEN ? tB : TLEN-1;
            x0 = pb0[tA]; x1 = pb1[tA]; x2 = pb2[tA];
            x3 = pb0[tB]; x4 = pb1[tB]; x5 = pb2[tB];
        }
    };

    float a0,a1,a2,a3,a4,a5;
    loadP(w0idx, a0,a1,a2,a3,a4,a5);

    for (int it = w0idx; it < NITERS; it += NWPB) {
        float n0,n1,n2,n3,n4,n5;
        loadP(it + NWPB, n0,n1,n2,n3,n4,n5);   // prefetch next tile

        FragU fAh, fBh;
        fAh.u[0] = pack2(a0, a1);  fAh.u[1] = pack2(a2, c0v);
        fBh.u[0] = pack2(a3, a4);  fBh.u[1] = pack2(a5, c0v);
        fAh.u[2]=wc2h; fAh.u[3]=wc3h;
        fBh.u[2]=wc2h; fBh.u[3]=wc3h;

        f32x16 accA = mfma_v(wphi, fAh, kZero);
        f32x16 accB = mfma_v(wphi, fBh, kZero);

        #pragma unroll
        for (int L = 0; L < 3; ++L) {
            FragU pA0, pA1, pB0, pB1;
            relu_pack(accA, pA0, pA1);
            relu_pack(accB, pB0, pB1);
            f32x16 tA2 = mfma_v(whi[L][0], pA0, biasS[L]);
            f32x16 tB2 = mfma_v(whi[L][0], pB0, biasS[L]);
            accA = mfma_v(whi[L][1], pA1, tA2);
            accB = mfma_v(whi[L][1], pB1, tB2);
        }

        FragU qA0, qA1, qB0, qB1;
        relu_pack(accA, qA0, qA1);
        relu_pack(accB, qB0, qB1);
        f32x16 oA = mfma_v(woF[0], qA0, kZero);
        f32x16 oB = mfma_v(woF[0], qB0, kZero);
        oA = mfma_v(woF[1], qA1, oA);
        oB = mfma_v(woF[1], qB1, oB);

        int t = it*64 + lane;
        if (t < TLEN) ob[t] = ((lane < 32) ? oA[0] : oB[0]) + bo;

        a0=n0; a1=n1; a2=n2; a3=n3; a4=n4; a5=n5;
    }
}

extern "C" void kernel_launch(void* const* d_in, const int* in_sizes, int n_in,
                              void* d_out, int out_size, void* d_ws, size_t ws_size,
                              hipStream_t stream) {
    const float* p     = (const float*)d_in[0];
    // d_in[1] = z (unused by reference)
    const float* c     = (const float*)d_in[2];
    const float* Wproj = (const float*)d_in[3];
    const float* bproj = (const float*)d_in[4];
    const float* Wp    = (const float*)d_in[5];
    const float* bp    = (const float*)d_in[6];
    const float* W0    = (const float*)d_in[7];
    const float* b0    = (const float*)d_in[8];
    const float* W1    = (const float*)d_in[9];
    const float* b1    = (const float*)d_in[10];
    const float* W2    = (const float*)d_in[11];
    const float* b2    = (const float*)d_in[12];
    const float* Wout  = (const float*)d_in[13];
    const float* bout  = (const float*)d_in[14];
    float* out = (float*)d_out;

    dim3 grid(NB*NJ*CHUNKS), block(256);
    ptf_decoder_kernel<<<grid, block, 0, stream>>>(
        p, c, Wproj, bproj, Wp, bp, W0, b0, W1, b1, W2, b2, Wout, bout, out);
}

// Round 15
// 33.408 us; speedup vs baseline: 1.5419x; 1.5419x over previous
//
#include <hip/hip_runtime.h>
#include <hip/hip_bf16.h>

#define NJ 24
#define TLEN 25000
#define NB 4
#define CHUNKS 20
#define NWPB (CHUNKS*4)           // waves per (b,j) = 80
#define NIT32 ((TLEN+31)/32)      // 782 tiles of 32 cols

typedef short short8 __attribute__((ext_vector_type(8)));
typedef short s16x2 __attribute__((ext_vector_type(2)));
typedef float f32x16 __attribute__((ext_vector_type(16)));

union FragU { unsigned u[4]; short8 s; };

// Safe f32x2 -> packed bf16x2, round-half-up: 3 VALU ops. Used where the
// producer is NOT an MFMA (inputs, weights) — no hazard exposure.
__device__ __forceinline__ unsigned pack2(float a, float b){
    unsigned ua = __float_as_uint(a) + 0x8000u;
    unsigned ub = __float_as_uint(b) + 0x8000u;
    return __builtin_amdgcn_perm(ub, ua, 0x07060302u);
}
__device__ __forceinline__ float bflo(unsigned u){
    union { unsigned v; float f; } t; t.v = u << 16; return t.f;
}

// HW packed cvt (RTNE), 1 op/pair — T12 recipe, HW-verified in m214v22.
// MUST be preceded by mfma_guard when consuming MFMA results: the
// compiler's MFMA hazard recognizer does not protect opaque asm readers
// (R5 failed exactly this way; R13 was the mirrored producer-side case).
__device__ __forceinline__ unsigned cvtpk(float a, float b){
    unsigned r;
    asm("v_cvt_pk_bf16_f32 %0, %1, %2" : "=v"(r) : "v"(a), "v"(b));
    return r;
}

// Pass-through hazard guard: 24 cyc of wave-local s_nop tied to the MFMA
// dest registers. Dataflow pins it after the MFMA and before any cvtpk
// that consumes the guarded value. Wave-local => co-resident waves fill it.
__device__ __forceinline__ f32x16 mfma_guard(f32x16 x){
    asm("s_nop 7\n\ts_nop 7\n\ts_nop 7" : "+v"(x));
    return x;
}

// packed bf16 relu via i16 max (bf16 bit patterns order as i16;
// negatives and -0.0 -> +0.0, positives kept). relu∘round == round∘relu.
__device__ __forceinline__ unsigned pkrelu(unsigned x){
    union { unsigned u; s16x2 v; } a, r;
    a.u = x;
    s16x2 z; z[0] = 0; z[1] = 0;
    r.v = __builtin_elementwise_max(a.v, z);
    return r.u;
}

__device__ __forceinline__ f32x16 mfma(const FragU &a, const FragU &b, f32x16 c){
    return __builtin_amdgcn_mfma_f32_32x32x16_bf16(a.s, b.s, c, 0, 0, 0);
}

__device__ __forceinline__ FragU mk1(unsigned w){
    FragU f; f.u[0] = w; f.u[1] = 0; f.u[2] = 0; f.u[3] = 0; return f;
}

// round-to-bf16 (HW cvt_pk) then packed relu; zero-shuffle layer chaining
// (pi-permuted channel labels compensated in the weight gather below).
// 16 VALU ops (was 32 with the add+add+perm pack) — relu_pack was ~73% of
// per-trip VALU, the binding resource per R9-R14 trip-slot arithmetic.
// CALLER must pass an mfma_guard()ed accumulator.
__device__ __forceinline__ void relu_pack(const f32x16 &acc, FragU &k0, FragU &k1){
    unsigned w[8];
    #pragma unroll
    for (int i = 0; i < 8; ++i) w[i] = pkrelu(cvtpk(acc[2*i], acc[2*i+1]));
    k0.u[0]=w[0]; k0.u[1]=w[1]; k0.u[2]=w[2]; k0.u[3]=w[3];
    k1.u[0]=w[4]; k1.u[1]=w[5]; k1.u[2]=w[6]; k1.u[3]=w[7];
}

// launch_bounds(256,2): DO NOT tighten — (256,4) spilled (R2: 303MB FETCH).
// R10 frame: 32-col trips, VGPR 52, occupancy 31% (best measured) — most
// headroom for the VALU cut to convert into wall-clock.
__global__ __launch_bounds__(256, 2) void ptf_decoder_kernel(
    const float* __restrict__ p,    const float* __restrict__ c,
    const float* __restrict__ Wproj,const float* __restrict__ bproj,
    const float* __restrict__ Wp,   const float* __restrict__ bp,
    const float* __restrict__ W0,   const float* __restrict__ b0,
    const float* __restrict__ W1,   const float* __restrict__ b1,
    const float* __restrict__ W2,   const float* __restrict__ b2,
    const float* __restrict__ Wout, const float* __restrict__ bout,
    float* __restrict__ out)
{
    __shared__ __align__(16) float ldsW[3][32][36];
    __shared__ __align__(16) float ldsWp[32][8];
    __shared__ __align__(16) float ldsB[3][32];
    __shared__ __align__(16) float ldsWo[32];

    const int tid = threadIdx.x;
    const int bj  = blockIdx.x % (NB*NJ);
    const int sub = blockIdx.x / (NB*NJ);
    const int b   = bj / NJ;
    const int j   = bj % NJ;

    // ---- stage this joint's weights into LDS (coalesced) ----
    {
        const float* Wl[3] = {W0, W1, W2};
        #pragma unroll
        for (int L = 0; L < 3; ++L) {
            int row = tid >> 3, c4 = tid & 7;
            float4 v = *reinterpret_cast<const float4*>(Wl[L] + ((size_t)(j*32 + row))*32 + c4*4);
            *reinterpret_cast<float4*>(&ldsW[L][row][c4*4]) = v;
        }
        {
            int row = tid >> 3, i8 = tid & 7;
            // col 7 carries b_p (first-layer bias rides k=7 with input 1.0)
            ldsWp[row][i8] = (i8 < 7) ? Wp[((size_t)(j*32 + row))*7 + i8]
                                      : bp[j*32 + row];
        }
        if      (tid < 32)  ldsB[0][tid]      = b0[j*32 + tid];
        else if (tid < 64)  ldsB[1][tid-32]   = b1[j*32 + tid-32];
        else if (tid < 96)  ldsB[2][tid-64]   = b2[j*32 + tid-64];
        else if (tid < 128) ldsWo[tid-96]     = Wout[j*32 + tid-96];
    }
    __syncthreads();

    const int lane = tid & 63;
    const int row  = lane & 31;
    const int h    = lane >> 5;

    // ---- per-lane weight fragments (bf16 hi only), pi-permuted k labels ----
    FragU whi[3][2];
    #pragma unroll
    for (int L = 0; L < 3; ++L) {
        #pragma unroll
        for (int kh = 0; kh < 2; ++kh) {
            const int g  = kh*2 + h;
            const int cA = (g >> 1)*4 + (g & 1);
            const float* base = &ldsW[L][row][0];
            float4 x = *reinterpret_cast<const float4*>(base + cA*4);
            float4 y = *reinterpret_cast<const float4*>(base + (cA+2)*4);
            whi[L][kh].u[0] = pack2(x.x, x.y);
            whi[L][kh].u[1] = pack2(x.z, x.w);
            whi[L][kh].u[2] = pack2(y.x, y.y);
            whi[L][kh].u[3] = pack2(y.z, y.w);
        }
    }
    // output layer: wo broadcast to all 32 rows, same pi-compensated gather
    FragU woF[2];
    #pragma unroll
    for (int kh = 0; kh < 2; ++kh) {
        const int g  = kh*2 + h;
        const int cA = (g >> 1)*4 + (g & 1);
        float4 x = *reinterpret_cast<const float4*>(&ldsWo[cA*4]);
        float4 y = *reinterpret_cast<const float4*>(&ldsWo[(cA+2)*4]);
        woF[kh].u[0] = pack2(x.x, x.y);
        woF[kh].u[1] = pack2(x.z, x.w);
        woF[kh].u[2] = pack2(y.x, y.y);
        woF[kh].u[3] = pack2(y.z, y.w);
    }
    // first layer: bf16 hi only (verified absmax 0.0156, 2.2x margin)
    FragU wphi;
    {
        float4 x = make_float4(0,0,0,0), y = make_float4(0,0,0,0);
        if (lane < 32) {
            x = *reinterpret_cast<const float4*>(&ldsWp[row][0]);
            y = *reinterpret_cast<const float4*>(&ldsWp[row][4]);
        }
        wphi.u[0] = pack2(x.x, x.y);
        wphi.u[1] = pack2(x.z, x.w);
        wphi.u[2] = pack2(y.x, y.y);
        wphi.u[3] = pack2(y.z, y.w);
    }

    // ---- hidden-layer biases as 1-reg A-fragments: k0=hi(b), k1=lo(b) ----
    unsigned biasA[3];
    #pragma unroll
    for (int L = 0; L < 3; ++L) {
        float bl = (h == 0) ? ldsB[L][row] : 0.f;
        unsigned t = pack2(bl, 0.f);
        float res = bl - bflo(t);
        biasA[L] = (h == 0) ? pack2(bl, res) : 0u;
    }
    const unsigned ones2 = (h == 0) ? 0x3f803f80u : 0u;   // {1.0bf16, 1.0bf16}

    // shared zero accumulator C (read-only)
    f32x16 kZero;
    #pragma unroll
    for (int r = 0; r < 16; ++r) kZero[r] = 0.f;

    // ---- c projection: c_proj[o] = dot(c[b], Wproj[j][o]) + bproj ----
    float cacc0, cacc1, cacc2, cacc3;
    {
        const float* cb  = c + (size_t)b*128;
        const float* wpj = Wproj + (size_t)j*4*128;
        float cl = cb[lane], chv = cb[lane + 64];
        cacc0 = cl*wpj[0*128+lane] + chv*wpj[0*128+lane+64];
        cacc1 = cl*wpj[1*128+lane] + chv*wpj[1*128+lane+64];
        cacc2 = cl*wpj[2*128+lane] + chv*wpj[2*128+lane+64];
        cacc3 = cl*wpj[3*128+lane] + chv*wpj[3*128+lane+64];
        #pragma unroll
        for (int off = 32; off >= 1; off >>= 1) {
            cacc0 += __shfl_xor(cacc0, off, 64);
            cacc1 += __shfl_xor(cacc1, off, 64);
            cacc2 += __shfl_xor(cacc2, off, 64);
            cacc3 += __shfl_xor(cacc3, off, 64);
        }
        cacc0 += bproj[j*4+0]; cacc1 += bproj[j*4+1];
        cacc2 += bproj[j*4+2]; cacc3 += bproj[j*4+3];
    }
    const float c0v = (lane < 32) ? cacc0 : 0.f;
    unsigned wc2h = pack2(cacc1, cacc2);
    unsigned wc3h = pack2(cacc3, 1.0f);   // k6=c3, k7=1.0 (bias slot)
    if (lane >= 32) { wc2h = 0; wc3h = 0; }
    const float bo = bout[j];

    // ---- main loop over 32-column tiles (single chain) ----
    const float* pb0 = p + ((size_t)(b*(NJ*3) + j*3 + 0))*TLEN;
    const float* pb1 = pb0 + TLEN;
    const float* pb2 = pb1 + TLEN;
    float* ob = out + ((size_t)(b*NJ + j))*TLEN;

    const int w0idx = sub*4 + (tid >> 6);

    auto loadP = [&](int itx, float&x0, float&x1, float&x2){
        x0=0.f; x1=0.f; x2=0.f;
        if (itx < NIT32 && lane < 32) {
            int t = itx*32 + lane;
            t = t < TLEN ? t : TLEN-1;
            x0 = pb0[t]; x1 = pb1[t]; x2 = pb2[t];
        }
    };

    float a0,a1,a2;
    loadP(w0idx, a0,a1,a2);

    for (int it = w0idx; it < NIT32; it += NWPB) {
        float n0,n1,n2;
        loadP(it + NWPB, n0,n1,n2);   // prefetch next tile

        // input fragment (safe 3-op pack: producer is global load, no hazard)
        FragU fh;
        fh.u[0] = pack2(a0, a1);
        fh.u[1] = pack2(a2, c0v);
        fh.u[2] = wc2h;
        fh.u[3] = wc3h;

        f32x16 acc = mfma(wphi, fh, kZero);

        #pragma unroll
        for (int L = 0; L < 3; ++L) {
            // data-independent bias surface; issues early, overlaps packing
            f32x16 bAcc = mfma(mk1(biasA[L]), mk1(ones2), kZero);
            FragU p0, p1;
            relu_pack(mfma_guard(acc), p0, p1);
            acc = mfma(whi[L][0], p0, bAcc);
            acc = mfma(whi[L][1], p1, acc);
        }

        // output layer: relu_pack + broadcast-wo MFMA (D[any reg] = dot)
        FragU q0, q1;
        relu_pack(mfma_guard(acc), q0, q1);
        f32x16 o = mfma(woF[0], q0, kZero);
        o = mfma(woF[1], q1, o);

        int t = it*32 + row;
        if (lane < 32 && t < TLEN) ob[t] = o[0] + bo;

        a0=n0; a1=n1; a2=n2;
    }
}

extern "C" void kernel_launch(void* const* d_in, const int* in_sizes, int n_in,
                              void* d_out, int out_size, void* d_ws, size_t ws_size,
                              hipStream_t stream) {
    const float* p     = (const float*)d_in[0];
    // d_in[1] = z (unused by reference)
    const float* c     = (const float*)d_in[2];
    const float* Wproj = (const float*)d_in[3];
    const float* bproj = (const float*)d_in[4];
    const float* Wp    = (const float*)d_in[5];
    const float* bp    = (const float*)d_in[6];
    const float* W0    = (const float*)d_in[7];
    const float* b0    = (const float*)d_in[8];
    const float* W1    = (const float*)d_in[9];
    const float* b1    = (const float*)d_in[10];
    const float* W2    = (const float*)d_in[11];
    const float* b2    = (const float*)d_in[12];
    const float* Wout  = (const float*)d_in[13];
    const float* bout  = (const float*)d_in[14];
    float* out = (float*)d_out;

    dim3 grid(NB*NJ*CHUNKS), block(256);
    ptf_decoder_kernel<<<grid, block, 0, stream>>>(
        p, c, Wproj, bproj, Wp, bp, W0, b0, W1, b1, W2, b2, Wout, bout, out);
}

// Round 16
// 32.518 us; speedup vs baseline: 1.5841x; 1.0274x over previous
//
#include <hip/hip_runtime.h>
#include <hip/hip_bf16.h>

#define NJ 24
#define TLEN 25000
#define NB 4
#define CHUNKS 20
#define NWPB (CHUNKS*4)           // waves per (b,j) = 80
#define NITERS ((TLEN+63)/64)     // 391 tiles of 64 cols

typedef short short8 __attribute__((ext_vector_type(8)));
typedef short s16x2 __attribute__((ext_vector_type(2)));
typedef float f32x16 __attribute__((ext_vector_type(16)));

union FragU { unsigned u[4]; short8 s; };

// Safe f32x2 -> packed bf16x2, round-half-up: 3 VALU ops. Used where the
// producer is NOT an MFMA (inputs, weights) — no hazard exposure.
__device__ __forceinline__ unsigned pack2(float a, float b){
    unsigned ua = __float_as_uint(a) + 0x8000u;
    unsigned ub = __float_as_uint(b) + 0x8000u;
    return __builtin_amdgcn_perm(ub, ua, 0x07060302u);
}
__device__ __forceinline__ float bflo(unsigned u){
    union { unsigned v; float f; } t; t.v = u << 16; return t.f;
}

// HW packed cvt (RTNE), 1 op/pair. MUST consume only mfma_guard()ed MFMA
// results: the compiler's MFMA hazard recognizer does not protect opaque
// asm readers (R5 failed unguarded; R15 passed guarded, absmax identical).
__device__ __forceinline__ unsigned cvtpk(float a, float b){
    unsigned r;
    asm("v_cvt_pk_bf16_f32 %0, %1, %2" : "=v"(r) : "v"(a), "v"(b));
    return r;
}

// Pass-through hazard guard: 24 cyc of wave-local s_nop tied to the MFMA
// dest registers (>= worst-case MFMA D-write -> VALU-read wait states).
// Dataflow pins it between the MFMA and any cvtpk consumer. Wave-local =>
// co-resident waves fill the bubble. Verified correct in R15.
__device__ __forceinline__ f32x16 mfma_guard(f32x16 x){
    asm("s_nop 7\n\ts_nop 7\n\ts_nop 7" : "+v"(x));
    return x;
}

// packed bf16 relu via i16 max (bf16 bit patterns order as i16;
// negatives -> +0.0). relu∘round == round∘relu.
__device__ __forceinline__ unsigned pkrelu(unsigned x){
    union { unsigned u; s16x2 v; } a, r;
    a.u = x;
    s16x2 z; z[0] = 0; z[1] = 0;
    r.v = __builtin_elementwise_max(a.v, z);
    return r.u;
}

__device__ __forceinline__ f32x16 mfma(const FragU &a, const FragU &b, f32x16 c){
    return __builtin_amdgcn_mfma_f32_32x32x16_bf16(a.s, b.s, c, 0, 0, 0);
}

__device__ __forceinline__ FragU mk1(unsigned w){
    FragU f; f.u[0] = w; f.u[1] = 0; f.u[2] = 0; f.u[3] = 0; return f;
}

// round-to-bf16 (HW cvt_pk) then packed relu; zero-shuffle layer chaining
// (pi-permuted channel labels compensated in the weight gather below).
// 16 VALU ops/pack. CALLER must pass an mfma_guard()ed accumulator.
__device__ __forceinline__ void relu_pack(const f32x16 &acc, FragU &k0, FragU &k1){
    unsigned w[8];
    #pragma unroll
    for (int i = 0; i < 8; ++i) w[i] = pkrelu(cvtpk(acc[2*i], acc[2*i+1]));
    k0.u[0]=w[0]; k0.u[1]=w[1]; k0.u[2]=w[2]; k0.u[3]=w[3];
    k1.u[0]=w[4]; k1.u[1]=w[5]; k1.u[2]=w[6]; k1.u[3]=w[7];
}

// launch_bounds(256,2): DO NOT tighten — (256,4) spilled (R2: 303MB FETCH).
// R16 = R9's 2-chain 64-col frame (per-trip overhead amortized over 2x
// columns, chain B covers chain A's MFMA latency; measured +6.5% vs
// 1-chain with old pack) + R15's guarded cvt_pk relu_pack (measured +13%).
__global__ __launch_bounds__(256, 2) void ptf_decoder_kernel(
    const float* __restrict__ p,    const float* __restrict__ c,
    const float* __restrict__ Wproj,const float* __restrict__ bproj,
    const float* __restrict__ Wp,   const float* __restrict__ bp,
    const float* __restrict__ W0,   const float* __restrict__ b0,
    const float* __restrict__ W1,   const float* __restrict__ b1,
    const float* __restrict__ W2,   const float* __restrict__ b2,
    const float* __restrict__ Wout, const float* __restrict__ bout,
    float* __restrict__ out)
{
    __shared__ __align__(16) float ldsW[3][32][36];
    __shared__ __align__(16) float ldsWp[32][8];
    __shared__ __align__(16) float ldsB[3][32];
    __shared__ __align__(16) float ldsWo[32];

    const int tid = threadIdx.x;
    const int bj  = blockIdx.x % (NB*NJ);
    const int sub = blockIdx.x / (NB*NJ);
    const int b   = bj / NJ;
    const int j   = bj % NJ;

    // ---- stage this joint's weights into LDS (coalesced) ----
    {
        const float* Wl[3] = {W0, W1, W2};
        #pragma unroll
        for (int L = 0; L < 3; ++L) {
            int row = tid >> 3, c4 = tid & 7;
            float4 v = *reinterpret_cast<const float4*>(Wl[L] + ((size_t)(j*32 + row))*32 + c4*4);
            *reinterpret_cast<float4*>(&ldsW[L][row][c4*4]) = v;
        }
        {
            int row = tid >> 3, i8 = tid & 7;
            // col 7 carries b_p (first-layer bias rides k=7 with input 1.0)
            ldsWp[row][i8] = (i8 < 7) ? Wp[((size_t)(j*32 + row))*7 + i8]
                                      : bp[j*32 + row];
        }
        if      (tid < 32)  ldsB[0][tid]      = b0[j*32 + tid];
        else if (tid < 64)  ldsB[1][tid-32]   = b1[j*32 + tid-32];
        else if (tid < 96)  ldsB[2][tid-64]   = b2[j*32 + tid-64];
        else if (tid < 128) ldsWo[tid-96]     = Wout[j*32 + tid-96];
    }
    __syncthreads();

    const int lane = tid & 63;
    const int row  = lane & 31;
    const int h    = lane >> 5;

    // ---- per-lane weight fragments (bf16 hi only), pi-permuted k labels ----
    FragU whi[3][2];
    #pragma unroll
    for (int L = 0; L < 3; ++L) {
        #pragma unroll
        for (int kh = 0; kh < 2; ++kh) {
            const int g  = kh*2 + h;
            const int cA = (g >> 1)*4 + (g & 1);
            const float* base = &ldsW[L][row][0];
            float4 x = *reinterpret_cast<const float4*>(base + cA*4);
            float4 y = *reinterpret_cast<const float4*>(base + (cA+2)*4);
            whi[L][kh].u[0] = pack2(x.x, x.y);
            whi[L][kh].u[1] = pack2(x.z, x.w);
            whi[L][kh].u[2] = pack2(y.x, y.y);
            whi[L][kh].u[3] = pack2(y.z, y.w);
        }
    }
    // output layer: wo broadcast to all 32 rows, same pi-compensated gather
    FragU woF[2];
    #pragma unroll
    for (int kh = 0; kh < 2; ++kh) {
        const int g  = kh*2 + h;
        const int cA = (g >> 1)*4 + (g & 1);
        float4 x = *reinterpret_cast<const float4*>(&ldsWo[cA*4]);
        float4 y = *reinterpret_cast<const float4*>(&ldsWo[(cA+2)*4]);
        woF[kh].u[0] = pack2(x.x, x.y);
        woF[kh].u[1] = pack2(x.z, x.w);
        woF[kh].u[2] = pack2(y.x, y.y);
        woF[kh].u[3] = pack2(y.z, y.w);
    }
    // first layer: bf16 hi only (verified absmax 0.0156, 2.2x margin)
    FragU wphi;
    {
        float4 x = make_float4(0,0,0,0), y = make_float4(0,0,0,0);
        if (lane < 32) {
            x = *reinterpret_cast<const float4*>(&ldsWp[row][0]);
            y = *reinterpret_cast<const float4*>(&ldsWp[row][4]);
        }
        wphi.u[0] = pack2(x.x, x.y);
        wphi.u[1] = pack2(x.z, x.w);
        wphi.u[2] = pack2(y.x, y.y);
        wphi.u[3] = pack2(y.z, y.w);
    }

    // ---- hidden-layer biases as 1-reg A-fragments: k0=hi(b), k1=lo(b) ----
    unsigned biasA[3];
    #pragma unroll
    for (int L = 0; L < 3; ++L) {
        float bl = (h == 0) ? ldsB[L][row] : 0.f;
        unsigned t = pack2(bl, 0.f);
        float res = bl - bflo(t);
        biasA[L] = (h == 0) ? pack2(bl, res) : 0u;
    }
    const unsigned ones2 = (h == 0) ? 0x3f803f80u : 0u;   // {1.0bf16, 1.0bf16}

    // shared zero accumulator C (read-only)
    f32x16 kZero;
    #pragma unroll
    for (int r = 0; r < 16; ++r) kZero[r] = 0.f;

    // ---- c projection: c_proj[o] = dot(c[b], Wproj[j][o]) + bproj ----
    float cacc0, cacc1, cacc2, cacc3;
    {
        const float* cb  = c + (size_t)b*128;
        const float* wpj = Wproj + (size_t)j*4*128;
        float cl = cb[lane], chv = cb[lane + 64];
        cacc0 = cl*wpj[0*128+lane] + chv*wpj[0*128+lane+64];
        cacc1 = cl*wpj[1*128+lane] + chv*wpj[1*128+lane+64];
        cacc2 = cl*wpj[2*128+lane] + chv*wpj[2*128+lane+64];
        cacc3 = cl*wpj[3*128+lane] + chv*wpj[3*128+lane+64];
        #pragma unroll
        for (int off = 32; off >= 1; off >>= 1) {
            cacc0 += __shfl_xor(cacc0, off, 64);
            cacc1 += __shfl_xor(cacc1, off, 64);
            cacc2 += __shfl_xor(cacc2, off, 64);
            cacc3 += __shfl_xor(cacc3, off, 64);
        }
        cacc0 += bproj[j*4+0]; cacc1 += bproj[j*4+1];
        cacc2 += bproj[j*4+2]; cacc3 += bproj[j*4+3];
    }
    const float c0v = (lane < 32) ? cacc0 : 0.f;
    unsigned wc2h = pack2(cacc1, cacc2);
    unsigned wc3h = pack2(cacc3, 1.0f);   // k6=c3, k7=1.0 (bias slot)
    if (lane >= 32) { wc2h = 0; wc3h = 0; }
    const float bo = bout[j];

    // ---- main loop over 64-column tiles (two 32-col chains A/B) ----
    const float* pb0 = p + ((size_t)(b*(NJ*3) + j*3 + 0))*TLEN;
    const float* pb1 = pb0 + TLEN;
    const float* pb2 = pb1 + TLEN;
    float* ob = out + ((size_t)(b*NJ + j))*TLEN;

    const int w0idx = sub*4 + (tid >> 6);

    auto loadP = [&](int itx, float&x0,float&x1,float&x2,float&x3,float&x4,float&x5){
        x0=0.f;x1=0.f;x2=0.f;x3=0.f;x4=0.f;x5=0.f;
        if (itx < NITERS && lane < 32) {
            int tA = itx*64 + lane;
            int tB = tA + 32;
            tA = tA < TLEN ? tA : TLEN-1;
            tB = tB < TLEN ? tB : TLEN-1;
            x0 = pb0[tA]; x1 = pb1[tA]; x2 = pb2[tA];
            x3 = pb0[tB]; x4 = pb1[tB]; x5 = pb2[tB];
        }
    };

    float a0,a1,a2,a3,a4,a5;
    loadP(w0idx, a0,a1,a2,a3,a4,a5);

    for (int it = w0idx; it < NITERS; it += NWPB) {
        float n0,n1,n2,n3,n4,n5;
        loadP(it + NWPB, n0,n1,n2,n3,n4,n5);   // prefetch next tile

        // input fragments (safe 3-op pack: producer is global load)
        FragU fAh, fBh;
        fAh.u[0] = pack2(a0, a1);  fAh.u[1] = pack2(a2, c0v);
        fBh.u[0] = pack2(a3, a4);  fBh.u[1] = pack2(a5, c0v);
        fAh.u[2]=wc2h; fAh.u[3]=wc3h;
        fBh.u[2]=wc2h; fBh.u[3]=wc3h;

        f32x16 accA = mfma(wphi, fAh, kZero);
        f32x16 accB = mfma(wphi, fBh, kZero);

        #pragma unroll
        for (int L = 0; L < 3; ++L) {
            // data-independent bias surface shared by both chains;
            // issues early, its latency hides under the packs.
            f32x16 bAcc = mfma(mk1(biasA[L]), mk1(ones2), kZero);
            FragU pA0, pA1, pB0, pB1;
            relu_pack(mfma_guard(accA), pA0, pA1);
            relu_pack(mfma_guard(accB), pB0, pB1);
            accA = mfma(whi[L][0], pA0, bAcc);
            accB = mfma(whi[L][0], pB0, bAcc);
            accA = mfma(whi[L][1], pA1, accA);
            accB = mfma(whi[L][1], pB1, accB);
        }

        // output layer: relu_pack + broadcast-wo MFMA (D[any reg] = dot)
        FragU qA0, qA1, qB0, qB1;
        relu_pack(mfma_guard(accA), qA0, qA1);
        relu_pack(mfma_guard(accB), qB0, qB1);
        f32x16 oA = mfma(woF[0], qA0, kZero);
        f32x16 oB = mfma(woF[0], qB0, kZero);
        oA = mfma(woF[1], qA1, oA);
        oB = mfma(woF[1], qB1, oB);

        int t = it*64 + lane;
        if (t < TLEN) ob[t] = ((lane < 32) ? oA[0] : oB[0]) + bo;

        a0=n0; a1=n1; a2=n2; a3=n3; a4=n4; a5=n5;
    }
}

extern "C" void kernel_launch(void* const* d_in, const int* in_sizes, int n_in,
                              void* d_out, int out_size, void* d_ws, size_t ws_size,
                              hipStream_t stream) {
    const float* p     = (const float*)d_in[0];
    // d_in[1] = z (unused by reference)
    const float* c     = (const float*)d_in[2];
    const float* Wproj = (const float*)d_in[3];
    const float* bproj = (const float*)d_in[4];
    const float* Wp    = (const float*)d_in[5];
    const float* bp    = (const float*)d_in[6];
    const float* W0    = (const float*)d_in[7];
    const float* b0    = (const float*)d_in[8];
    const float* W1    = (const float*)d_in[9];
    const float* b1    = (const float*)d_in[10];
    const float* W2    = (const float*)d_in[11];
    const float* b2    = (const float*)d_in[12];
    const float* Wout  = (const float*)d_in[13];
    const float* bout  = (const float*)d_in[14];
    float* out = (float*)d_out;

    dim3 grid(NB*NJ*CHUNKS), block(256);
    ptf_decoder_kernel<<<grid, block, 0, stream>>>(
        p, c, Wproj, bproj, Wp, bp, W0, b0, W1, b1, W2, b2, Wout, bout, out);
}

// Round 17
// 31.541 us; speedup vs baseline: 1.6332x; 1.0310x over previous
//
#include <hip/hip_runtime.h>
#include <hip/hip_bf16.h>

#define NJ 24
#define TLEN 25000
#define NB 4
#define CHUNKS 20
#define NWPB (CHUNKS*4)           // waves per (b,j) = 80
#define NITERS ((TLEN+63)/64)     // 391 tiles of 64 cols

typedef short short8 __attribute__((ext_vector_type(8)));
typedef short s16x2 __attribute__((ext_vector_type(2)));
typedef float f32x16 __attribute__((ext_vector_type(16)));

union FragU { unsigned u[4]; short8 s; };

// Safe f32x2 -> packed bf16x2, round-half-up: 3 VALU ops. Used where the
// producer is NOT an MFMA (inputs, weights) — no hazard exposure.
__device__ __forceinline__ unsigned pack2(float a, float b){
    unsigned ua = __float_as_uint(a) + 0x8000u;
    unsigned ub = __float_as_uint(b) + 0x8000u;
    return __builtin_amdgcn_perm(ub, ua, 0x07060302u);
}
__device__ __forceinline__ float bflo(unsigned u){
    union { unsigned v; float f; } t; t.v = u << 16; return t.f;
}

// HW packed cvt (RTNE), 1 op/pair. MUST consume only guard2()ed MFMA
// results: the compiler's MFMA hazard recognizer does not protect opaque
// asm readers (R5 failed unguarded; R15/R16 passed guarded, absmax clean).
__device__ __forceinline__ unsigned cvtpk(float a, float b){
    unsigned r;
    asm("v_cvt_pk_bf16_f32 %0, %1, %2" : "=v"(r) : "v"(a), "v"(b));
    return r;
}

// Dual hazard guard: ONE 24-cyc wave-local s_nop block covering BOTH
// chains' accumulators (both MFMAs are dataflow-ordered before it; the
// younger accB is >=24cyc old before any cvtpk can read it — same margin
// as R15's proven single guard). Halves guard count vs R16: 8 -> 4/trip.
__device__ __forceinline__ void guard2(f32x16 &x, f32x16 &y){
    asm("s_nop 7\n\ts_nop 7\n\ts_nop 7" : "+v"(x), "+v"(y));
}

// packed bf16 relu via i16 max (bf16 bit patterns order as i16;
// negatives -> +0.0). relu∘round == round∘relu.
__device__ __forceinline__ unsigned pkrelu(unsigned x){
    union { unsigned u; s16x2 v; } a, r;
    a.u = x;
    s16x2 z; z[0] = 0; z[1] = 0;
    r.v = __builtin_elementwise_max(a.v, z);
    return r.u;
}

__device__ __forceinline__ f32x16 mfma(const FragU &a, const FragU &b, f32x16 c){
    return __builtin_amdgcn_mfma_f32_32x32x16_bf16(a.s, b.s, c, 0, 0, 0);
}

__device__ __forceinline__ FragU mk1(unsigned w){
    FragU f; f.u[0] = w; f.u[1] = 0; f.u[2] = 0; f.u[3] = 0; return f;
}

// round-to-bf16 (HW cvt_pk) then packed relu; zero-shuffle layer chaining
// (pi-permuted channel labels compensated in the weight gather below).
// 16 VALU ops/pack. CALLER must guard2() the accumulators first.
__device__ __forceinline__ void relu_pack(const f32x16 &acc, FragU &k0, FragU &k1){
    unsigned w[8];
    #pragma unroll
    for (int i = 0; i < 8; ++i) w[i] = pkrelu(cvtpk(acc[2*i], acc[2*i+1]));
    k0.u[0]=w[0]; k0.u[1]=w[1]; k0.u[2]=w[2]; k0.u[3]=w[3];
    k1.u[0]=w[4]; k1.u[1]=w[5]; k1.u[2]=w[6]; k1.u[3]=w[7];
}

// launch_bounds(256,2): DO NOT tighten — (256,4) spilled (R2: 303MB FETCH).
// R17 = R16 + (a) bias surfaces hoisted to prologue (in-loop bias-MFMA was
// a R7 register-saving move; R10/R12 proved regs aren't binding — so spend
// 48 regs to delete 3 MFMAs/trip) + (b) guard2 merging (4 guards/trip).
__global__ __launch_bounds__(256, 2) void ptf_decoder_kernel(
    const float* __restrict__ p,    const float* __restrict__ c,
    const float* __restrict__ Wproj,const float* __restrict__ bproj,
    const float* __restrict__ Wp,   const float* __restrict__ bp,
    const float* __restrict__ W0,   const float* __restrict__ b0,
    const float* __restrict__ W1,   const float* __restrict__ b1,
    const float* __restrict__ W2,   const float* __restrict__ b2,
    const float* __restrict__ Wout, const float* __restrict__ bout,
    float* __restrict__ out)
{
    __shared__ __align__(16) float ldsW[3][32][36];
    __shared__ __align__(16) float ldsWp[32][8];
    __shared__ __align__(16) float ldsB[3][32];
    __shared__ __align__(16) float ldsWo[32];

    const int tid = threadIdx.x;
    const int bj  = blockIdx.x % (NB*NJ);
    const int sub = blockIdx.x / (NB*NJ);
    const int b   = bj / NJ;
    const int j   = bj % NJ;

    // ---- stage this joint's weights into LDS (coalesced) ----
    {
        const float* Wl[3] = {W0, W1, W2};
        #pragma unroll
        for (int L = 0; L < 3; ++L) {
            int row = tid >> 3, c4 = tid & 7;
            float4 v = *reinterpret_cast<const float4*>(Wl[L] + ((size_t)(j*32 + row))*32 + c4*4);
            *reinterpret_cast<float4*>(&ldsW[L][row][c4*4]) = v;
        }
        {
            int row = tid >> 3, i8 = tid & 7;
            // col 7 carries b_p (first-layer bias rides k=7 with input 1.0)
            ldsWp[row][i8] = (i8 < 7) ? Wp[((size_t)(j*32 + row))*7 + i8]
                                      : bp[j*32 + row];
        }
        if      (tid < 32)  ldsB[0][tid]      = b0[j*32 + tid];
        else if (tid < 64)  ldsB[1][tid-32]   = b1[j*32 + tid-32];
        else if (tid < 96)  ldsB[2][tid-64]   = b2[j*32 + tid-64];
        else if (tid < 128) ldsWo[tid-96]     = Wout[j*32 + tid-96];
    }
    __syncthreads();

    const int lane = tid & 63;
    const int row  = lane & 31;
    const int h    = lane >> 5;

    // ---- per-lane weight fragments (bf16 hi only), pi-permuted k labels ----
    FragU whi[3][2];
    #pragma unroll
    for (int L = 0; L < 3; ++L) {
        #pragma unroll
        for (int kh = 0; kh < 2; ++kh) {
            const int g  = kh*2 + h;
            const int cA = (g >> 1)*4 + (g & 1);
            const float* base = &ldsW[L][row][0];
            float4 x = *reinterpret_cast<const float4*>(base + cA*4);
            float4 y = *reinterpret_cast<const float4*>(base + (cA+2)*4);
            whi[L][kh].u[0] = pack2(x.x, x.y);
            whi[L][kh].u[1] = pack2(x.z, x.w);
            whi[L][kh].u[2] = pack2(y.x, y.y);
            whi[L][kh].u[3] = pack2(y.z, y.w);
        }
    }
    // output layer: wo broadcast to all 32 rows, same pi-compensated gather
    FragU woF[2];
    #pragma unroll
    for (int kh = 0; kh < 2; ++kh) {
        const int g  = kh*2 + h;
        const int cA = (g >> 1)*4 + (g & 1);
        float4 x = *reinterpret_cast<const float4*>(&ldsWo[cA*4]);
        float4 y = *reinterpret_cast<const float4*>(&ldsWo[(cA+2)*4]);
        woF[kh].u[0] = pack2(x.x, x.y);
        woF[kh].u[1] = pack2(x.z, x.w);
        woF[kh].u[2] = pack2(y.x, y.y);
        woF[kh].u[3] = pack2(y.z, y.w);
    }
    // first layer: bf16 hi only (verified absmax 0.0156, 2.2x margin)
    FragU wphi;
    {
        float4 x = make_float4(0,0,0,0), y = make_float4(0,0,0,0);
        if (lane < 32) {
            x = *reinterpret_cast<const float4*>(&ldsWp[row][0]);
            y = *reinterpret_cast<const float4*>(&ldsWp[row][4]);
        }
        wphi.u[0] = pack2(x.x, x.y);
        wphi.u[1] = pack2(x.z, x.w);
        wphi.u[2] = pack2(y.x, y.y);
        wphi.u[3] = pack2(y.z, y.w);
    }

    // shared zero accumulator C (read-only)
    f32x16 kZero;
    #pragma unroll
    for (int r = 0; r < 16; ++r) kZero[r] = 0.f;

    // ---- hidden-layer bias SURFACES, prologue-computed (was in-loop:
    //      3 MFMAs/trip). D[r][c] = hi(b_r)+lo(b_r) = b_r for all c.
    //      Same arithmetic as R7-R16, computed once. ----
    f32x16 biasS[3];
    #pragma unroll
    for (int L = 0; L < 3; ++L) {
        float bl = (h == 0) ? ldsB[L][row] : 0.f;
        unsigned t = pack2(bl, 0.f);
        float res = bl - bflo(t);
        unsigned biasw = (h == 0) ? pack2(bl, res) : 0u;
        unsigned ones2 = (h == 0) ? 0x3f803f80u : 0u;
        biasS[L] = mfma(mk1(biasw), mk1(ones2), kZero);
    }

    // ---- c projection: c_proj[o] = dot(c[b], Wproj[j][o]) + bproj ----
    float cacc0, cacc1, cacc2, cacc3;
    {
        const float* cb  = c + (size_t)b*128;
        const float* wpj = Wproj + (size_t)j*4*128;
        float cl = cb[lane], chv = cb[lane + 64];
        cacc0 = cl*wpj[0*128+lane] + chv*wpj[0*128+lane+64];
        cacc1 = cl*wpj[1*128+lane] + chv*wpj[1*128+lane+64];
        cacc2 = cl*wpj[2*128+lane] + chv*wpj[2*128+lane+64];
        cacc3 = cl*wpj[3*128+lane] + chv*wpj[3*128+lane+64];
        #pragma unroll
        for (int off = 32; off >= 1; off >>= 1) {
            cacc0 += __shfl_xor(cacc0, off, 64);
            cacc1 += __shfl_xor(cacc1, off, 64);
            cacc2 += __shfl_xor(cacc2, off, 64);
            cacc3 += __shfl_xor(cacc3, off, 64);
        }
        cacc0 += bproj[j*4+0]; cacc1 += bproj[j*4+1];
        cacc2 += bproj[j*4+2]; cacc3 += bproj[j*4+3];
    }
    const float c0v = (lane < 32) ? cacc0 : 0.f;
    unsigned wc2h = pack2(cacc1, cacc2);
    unsigned wc3h = pack2(cacc3, 1.0f);   // k6=c3, k7=1.0 (bias slot)
    if (lane >= 32) { wc2h = 0; wc3h = 0; }
    const float bo = bout[j];

    // ---- main loop over 64-column tiles (two 32-col chains A/B) ----
    const float* pb0 = p + ((size_t)(b*(NJ*3) + j*3 + 0))*TLEN;
    const float* pb1 = pb0 + TLEN;
    const float* pb2 = pb1 + TLEN;
    float* ob = out + ((size_t)(b*NJ + j))*TLEN;

    const int w0idx = sub*4 + (tid >> 6);

    auto loadP = [&](int itx, float&x0,float&x1,float&x2,float&x3,float&x4,float&x5){
        x0=0.f;x1=0.f;x2=0.f;x3=0.f;x4=0.f;x5=0.f;
        if (itx < NITERS && lane < 32) {
            int tA = itx*64 + lane;
            int tB = tA + 32;
            tA = tA < TLEN ? tA : TLEN-1;
            tB = tB < TLEN ? tB : TLEN-1;
            x0 = pb0[tA]; x1 = pb1[tA]; x2 = pb2[tA];
            x3 = pb0[tB]; x4 = pb1[tB]; x5 = pb2[tB];
        }
    };

    float a0,a1,a2,a3,a4,a5;
    loadP(w0idx, a0,a1,a2,a3,a4,a5);

    for (int it = w0idx; it < NITERS; it += NWPB) {
        float n0,n1,n2,n3,n4,n5;
        loadP(it + NWPB, n0,n1,n2,n3,n4,n5);   // prefetch next tile

        // input fragments (safe 3-op pack: producer is global load)
        FragU fAh, fBh;
        fAh.u[0] = pack2(a0, a1);  fAh.u[1] = pack2(a2, c0v);
        fBh.u[0] = pack2(a3, a4);  fBh.u[1] = pack2(a5, c0v);
        fAh.u[2]=wc2h; fAh.u[3]=wc3h;
        fBh.u[2]=wc2h; fBh.u[3]=wc3h;

        f32x16 accA = mfma(wphi, fAh, kZero);
        f32x16 accB = mfma(wphi, fBh, kZero);

        #pragma unroll
        for (int L = 0; L < 3; ++L) {
            guard2(accA, accB);
            FragU pA0, pA1, pB0, pB1;
            relu_pack(accA, pA0, pA1);
            relu_pack(accB, pB0, pB1);
            accA = mfma(whi[L][0], pA0, biasS[L]);
            accB = mfma(whi[L][0], pB0, biasS[L]);
            accA = mfma(whi[L][1], pA1, accA);
            accB = mfma(whi[L][1], pB1, accB);
        }

        // output layer: relu_pack + broadcast-wo MFMA (D[any reg] = dot)
        guard2(accA, accB);
        FragU qA0, qA1, qB0, qB1;
        relu_pack(accA, qA0, qA1);
        relu_pack(accB, qB0, qB1);
        f32x16 oA = mfma(woF[0], qA0, kZero);
        f32x16 oB = mfma(woF[0], qB0, kZero);
        oA = mfma(woF[1], qA1, oA);
        oB = mfma(woF[1], qB1, oB);

        int t = it*64 + lane;
        if (t < TLEN) ob[t] = ((lane < 32) ? oA[0] : oB[0]) + bo;

        a0=n0; a1=n1; a2=n2; a3=n3; a4=n4; a5=n5;
    }
}

extern "C" void kernel_launch(void* const* d_in, const int* in_sizes, int n_in,
                              void* d_out, int out_size, void* d_ws, size_t ws_size,
                              hipStream_t stream) {
    const float* p     = (const float*)d_in[0];
    // d_in[1] = z (unused by reference)
    const float* c     = (const float*)d_in[2];
    const float* Wproj = (const float*)d_in[3];
    const float* bproj = (const float*)d_in[4];
    const float* Wp    = (const float*)d_in[5];
    const float* bp    = (const float*)d_in[6];
    const float* W0    = (const float*)d_in[7];
    const float* b0    = (const float*)d_in[8];
    const float* W1    = (const float*)d_in[9];
    const float* b1    = (const float*)d_in[10];
    const float* W2    = (const float*)d_in[11];
    const float* b2    = (const float*)d_in[12];
    const float* Wout  = (const float*)d_in[13];
    const float* bout  = (const float*)d_in[14];
    float* out = (float*)d_out;

    dim3 grid(NB*NJ*CHUNKS), block(256);
    ptf_decoder_kernel<<<grid, block, 0, stream>>>(
        p, c, Wproj, bproj, Wp, bp, W0, b0, W1, b1, W2, b2, Wout, bout, out);
}